// Round 7
// baseline (197.421 us; speedup 1.0000x reference)
//
#include <hip/hip_runtime.h>
#include <hip/hip_bf16.h>

// MHA: B=2, T=2048, C=1024, H=16, Dh=64. fp32 in/out, bf16 MFMA internally.
// ws layout (bf16 elems): [0,4M): xb. [4M,7M): wq|wk|wv. [7M,8M): wo.
// [8M,12M): Q. [12M,16M): K. [16M,20M): Vt (written by QKV gemm epilogue).
// [20M,24M): AO.  Total 48 MB.

typedef __bf16 bf16;
typedef __attribute__((ext_vector_type(8))) __bf16 bf16x8;
typedef __attribute__((ext_vector_type(4))) __bf16 bf16x4;
typedef __attribute__((ext_vector_type(4))) float floatx4;

#define LOG2E 1.44269504088896340736f

__device__ __forceinline__ void gl2lds16(const void* g, void* l) {
  __builtin_amdgcn_global_load_lds((const __attribute__((address_space(1))) void*)g,
                                   (__attribute__((address_space(3))) void*)l, 16, 0, 0);
}

// ---------------- cast fp32 -> bf16 (x | wq | wk | wv | wo) ----------------
__global__ __launch_bounds__(256) void cast_all(
    const float* __restrict__ x, const float* __restrict__ wq,
    const float* __restrict__ wk, const float* __restrict__ wv,
    const float* __restrict__ wo, bf16* __restrict__ dst)
{
  const size_t M1 = (size_t)1 << 20;
  size_t i4 = ((size_t)blockIdx.x * 256 + threadIdx.x) * 4;
  const float* src = x;
  size_t off = i4;
  if (i4 >= 4 * M1) {
    size_t r = i4 - 4 * M1;
    int seg = (int)(r >> 20);
    off = r & (M1 - 1);
    src = (seg == 0) ? wq : (seg == 1) ? wk : (seg == 2) ? wv : wo;
  }
  float4 f = *(const float4*)(src + off);
  bf16x4 o = { (bf16)f.x, (bf16)f.y, (bf16)f.z, (bf16)f.w };
  *(bf16x4*)(dst + i4) = o;
}

// ---------------- GEMM: out[m][n] = sum_k A[m][k]*W[n][k] + bias[n] ----------------
// BK=64, xor-swizzled 16B LDS groups (conflict-minimal reads), 32 MFMA/barrier.
// QKV: mat0 -> Q (bf16, pre-scaled), mat1 -> K, mat2 -> Vt[bh][d][t].
template<bool F32OUT, bool QKV, int BN>
__global__ __launch_bounds__(256, 3) void gemm_bt(
    const bf16* __restrict__ A, const bf16* __restrict__ Wb,
    const float* __restrict__ bq, const float* __restrict__ bk,
    const float* __restrict__ bv, void* __restrict__ outb,
    bf16* __restrict__ vt, int M, int N, int K, float qscale)
{
  __shared__ bf16 As[128 * 64];
  __shared__ bf16 Bs[BN * 64];
  const int tid = threadIdx.x;
  const int lane = tid & 63;
  const int wid = tid >> 6;
  const int l15 = lane & 15, l4 = lane >> 4;
  constexpr int I = (BN == 128) ? 4 : 2;
  const int wr = (BN == 128) ? (wid >> 1) : wid;
  const int wc = (BN == 128) ? (wid & 1) : 0;

  const bf16* W;
  const float* bias;
  float osc = 1.0f;
  int n0, mat = 0;
  bf16* outh;
  float* outf;
  if (QKV) {
    mat = blockIdx.x >> 3;
    n0 = (blockIdx.x & 7) << 7;
    W = Wb + ((size_t)mat << 20);
    bias = (mat == 0) ? bq : (mat == 1 ? bk : bv);
    if (mat == 0) osc = qscale;
    outh = (bf16*)outb + ((size_t)mat << 22);
    outf = nullptr;
  } else {
    n0 = blockIdx.x * BN;
    W = Wb;
    bias = bq;
    outf = (float*)outb;
    outh = nullptr;
  }
  const int m0 = blockIdx.y << 7;

  floatx4 acc[I][4] = {};

  for (int k0 = 0; k0 < K; k0 += 64) {
#pragma unroll
    for (int it = 0; it < 4; ++it) {
      int c = it * 256 + tid;
      int row = c >> 3, gs = ((c & 7) ^ (row & 7)) << 3;
      gl2lds16(A + (size_t)(m0 + row) * K + k0 + gs, As + c * 8);
    }
#pragma unroll
    for (int it = 0; it < BN / 32; ++it) {
      int c = it * 256 + tid;
      int row = c >> 3, gs = ((c & 7) ^ (row & 7)) << 3;
      gl2lds16(W + (size_t)(n0 + row) * K + k0 + gs, Bs + c * 8);
    }
    __syncthreads();
#pragma unroll
    for (int kk = 0; kk < 2; ++kk) {
      bf16x8 af[I], bfr[4];
#pragma unroll
      for (int i = 0; i < I; ++i) {
        int r = wr * (I * 16) + i * 16 + l15;
        int g = (kk * 4 + l4) ^ (r & 7);
        af[i] = *(const bf16x8*)(As + r * 64 + g * 8);
      }
#pragma unroll
      for (int j = 0; j < 4; ++j) {
        int r = wc * 64 + j * 16 + l15;
        int g = (kk * 4 + l4) ^ (r & 7);
        bfr[j] = *(const bf16x8*)(Bs + r * 64 + g * 8);
      }
#pragma unroll
      for (int i = 0; i < I; ++i)
#pragma unroll
        for (int j = 0; j < 4; ++j)
          acc[i][j] = __builtin_amdgcn_mfma_f32_16x16x32_bf16(af[i], bfr[j], acc[i][j], 0, 0, 0);
    }
    __syncthreads();
  }

  if (QKV && mat == 2) {
    // write Vt[bh][d][t]: lane's 4 rg rows are contiguous t -> b64 stores
#pragma unroll
    for (int j = 0; j < 4; ++j) {
      int col = n0 + wc * 64 + j * 16 + l15;
      float bv_ = bias[col];
      int h = col >> 6, d = col & 63;
#pragma unroll
      for (int i = 0; i < I; ++i) {
        int row = m0 + wr * (I * 16) + i * 16 + l4 * 4;
        int bb = row >> 11, t = row & 2047;
        bf16x4 pk;
#pragma unroll
        for (int rg = 0; rg < 4; ++rg) pk[rg] = (bf16)(acc[i][j][rg] + bv_);
        *(bf16x4*)(vt + (((size_t)(bb * 16 + h)) << 17) + ((size_t)d << 11) + t) = pk;
      }
    }
    return;
  }

#pragma unroll
  for (int j = 0; j < 4; ++j) {
    int col = n0 + wc * 64 + j * 16 + l15;
    float bv_ = bias[col];
#pragma unroll
    for (int i = 0; i < I; ++i) {
#pragma unroll
      for (int rg = 0; rg < 4; ++rg) {
        int row = m0 + wr * (I * 16) + i * 16 + l4 * 4 + rg;
        float v = (acc[i][j][rg] + bv_) * osc;
        if (F32OUT) outf[(size_t)row * N + col] = v;
        else        outh[(size_t)row * N + col] = (bf16)v;
      }
    }
  }
}

// ---------------- fused causal flash attention ----------------
// grid 512 1-D: bh = u&31 (fastest -> head-local L2/XCD), p = u>>5 (0..15),
// q-tile PAIR (15-p, p) -> uniform 34 K-tiles/block. 128 q-rows/block,
// 32/wave (Q register B-frags reused across the K fragment reads -> half
// the per-work LDS traffic). S and O both computed TRANSPOSED so softmax
// stats, alpha and 1/l are per-lane. K-tile 64, double-buffered gl2lds
// staging across the pair, ONE barrier per tile. Ps stride 68 (bank-minimal).
// Q pre-scaled by 1/sqrt(Dh)*log2e.
__global__ __launch_bounds__(256, 2) void attn_kernel(
    const bf16* __restrict__ Q, const bf16* __restrict__ Kg,
    const bf16* __restrict__ Vt, bf16* __restrict__ AO)
{
  constexpr int T = 2048, C = 1024;
  __shared__ bf16 Ks[2][64 * 64];   // [j][d], xor-swizzled 16B groups
  __shared__ bf16 Vts[2][64 * 64];  // [d][j], xor-swizzled 16B groups
  __shared__ bf16 Ps[4][32 * 68];   // per-wave P^T [q_local][j_local]

  const int tid = threadIdx.x;
  const int lane = tid & 63;
  const int w = tid >> 6;
  const int l15 = lane & 15, l4 = lane >> 4;

  const int u = blockIdx.x;
  const int bh = u & 31;
  const int p = u >> 5;
  const size_t base = ((size_t)(bh >> 4) * T) * C + (bh & 15) * 64;
  const bf16* vtb = Vt + ((size_t)bh << 17);

  auto stageK = [&](int j0, int bufi) {
#pragma unroll
    for (int it = 0; it < 2; ++it) {
      int c = it * 256 + tid;
      int row = c >> 3, s = (c & 7) ^ (row & 7);
      gl2lds16(Kg + base + (size_t)(j0 + row) * C + s * 8, &Ks[bufi][c * 8]);
    }
  };
  auto stageV = [&](int j0, int bufi) {
#pragma unroll
    for (int it = 0; it < 2; ++it) {
      int c = it * 256 + tid;
      int row = c >> 3, s = (c & 7) ^ (row & 7);
      gl2lds16(vtb + ((size_t)row << 11) + j0 + s * 8, &Vts[bufi][c * 8]);
    }
  };

  const int qts[2] = { 15 - p, p };
  int g = 0;  // global tile counter -> LDS buffer alternation
  stageK(0, 0);
  stageV(0, 0);

  for (int seg = 0; seg < 2; ++seg) {
    const int qt = qts[seg];
    const int q0 = qt << 7;
    const int nkt = 2 * qt + 2;
    const int qwave = q0 + w * 32;

    // Q B-frags in registers: wave w owns rows qwave + tq*16 + l15
    bf16x8 qf[2][2];
#pragma unroll
    for (int tq = 0; tq < 2; ++tq) {
      const bf16* qp = Q + base + (size_t)(qwave + tq * 16 + l15) * C + l4 * 8;
      qf[tq][0] = *(const bf16x8*)(qp);
      qf[tq][1] = *(const bf16x8*)(qp + 32);
    }
    floatx4 o[2][4] = {};      // O^T: rows d, col q
    float mrow[2] = {-1e38f, -1e38f};
    float lrow[2] = {0.f, 0.f};

    for (int jt = 0; jt < nkt; ++jt, ++g) {
      __syncthreads();  // staging of tile g visible; buf g^1 reads done
      const int cur = g & 1;
      if (jt + 1 < nkt) {
        stageK((jt + 1) << 6, cur ^ 1);
        stageV((jt + 1) << 6, cur ^ 1);
      } else if (seg == 0) {
        stageK(0, cur ^ 1);  // first tile of segment B
        stageV(0, cur ^ 1);
      }
      const int j0 = jt << 6;
      if (j0 > qwave + 31) continue;  // wave-uniform: fully masked tile

      // ---- S^T = K Q^T : s4[tj][tq], row j = tj*16+l4*4+rg, col q
      floatx4 s4[4][2] = {};
#pragma unroll
      for (int kk = 0; kk < 2; ++kk) {
        bf16x8 kf[4];
#pragma unroll
        for (int tj = 0; tj < 4; ++tj) {
          int r = tj * 16 + l15;
          int sl = (kk * 4 + l4) ^ (r & 7);
          kf[tj] = *(const bf16x8*)(&Ks[cur][r * 64 + sl * 8]);
        }
#pragma unroll
        for (int tj = 0; tj < 4; ++tj)
#pragma unroll
          for (int tq = 0; tq < 2; ++tq)
            s4[tj][tq] = __builtin_amdgcn_mfma_f32_16x16x32_bf16(kf[tj], qf[tq][kk], s4[tj][tq], 0, 0, 0);
      }

      // ---- causal mask (j > q): only near-diagonal tiles
      if (j0 + 63 > qwave) {
#pragma unroll
        for (int tj = 0; tj < 4; ++tj) {
          int j = j0 + tj * 16 + l4 * 4;
#pragma unroll
          for (int tq = 0; tq < 2; ++tq) {
            int q = qwave + tq * 16 + l15;
#pragma unroll
            for (int rg = 0; rg < 4; ++rg)
              if (j + rg > q) s4[tj][tq][rg] = -3e38f;
          }
        }
      }

      // ---- online softmax: lane owns row q, stats in-register + 2 shuffles
      float al[2];
#pragma unroll
      for (int tq = 0; tq < 2; ++tq) {
        float mx = -3e38f;
#pragma unroll
        for (int tj = 0; tj < 4; ++tj)
#pragma unroll
          for (int rg = 0; rg < 4; ++rg)
            mx = fmaxf(mx, s4[tj][tq][rg]);
        mx = fmaxf(mx, __shfl_xor(mx, 16, 64));
        mx = fmaxf(mx, __shfl_xor(mx, 32, 64));
        float mnew = fmaxf(mrow[tq], mx);
        al[tq] = __builtin_amdgcn_exp2f(mrow[tq] - mnew);
        mrow[tq] = mnew;
        float psum = 0.f;
#pragma unroll
        for (int tj = 0; tj < 4; ++tj)
#pragma unroll
          for (int rg = 0; rg < 4; ++rg) {
            float e = __builtin_amdgcn_exp2f(s4[tj][tq][rg] - mnew);
            s4[tj][tq][rg] = e;
            psum += e;
          }
        psum += __shfl_xor(psum, 16, 64);
        psum += __shfl_xor(psum, 32, 64);
        lrow[tq] = lrow[tq] * al[tq] + psum;
      }

      // ---- P -> LDS, packed b64 (rg contiguous): Ps[q_local][j_local]
#pragma unroll
      for (int tq = 0; tq < 2; ++tq)
#pragma unroll
        for (int tj = 0; tj < 4; ++tj) {
          bf16x4 pk = { (bf16)s4[tj][tq][0], (bf16)s4[tj][tq][1],
                        (bf16)s4[tj][tq][2], (bf16)s4[tj][tq][3] };
          *(bf16x4*)(&Ps[w][(tq * 16 + l15) * 68 + tj * 16 + l4 * 4]) = pk;
        }

      // ---- rescale O^T by alpha (per-lane, no shuffles)
#pragma unroll
      for (int tq = 0; tq < 2; ++tq)
#pragma unroll
        for (int td = 0; td < 4; ++td)
#pragma unroll
          for (int rg = 0; rg < 4; ++rg)
            o[tq][td][rg] *= al[tq];

      // ---- O^T += Vt P^T  (A = Vt frag shared across tq, B = P^T frag)
#pragma unroll
      for (int tk = 0; tk < 2; ++tk) {
        bf16x8 pf[2];
#pragma unroll
        for (int tq = 0; tq < 2; ++tq)
          pf[tq] = *(const bf16x8*)(&Ps[w][(tq * 16 + l15) * 68 + tk * 32 + l4 * 8]);
#pragma unroll
        for (int td = 0; td < 4; ++td) {
          int r = td * 16 + l15;
          int sl = (tk * 4 + l4) ^ (r & 7);
          bf16x8 vf = *(const bf16x8*)(&Vts[cur][r * 64 + sl * 8]);
#pragma unroll
          for (int tq = 0; tq < 2; ++tq)
            o[tq][td] = __builtin_amdgcn_mfma_f32_16x16x32_bf16(vf, pf[tq], o[tq][td], 0, 0, 0);
        }
      }
    }

    // ---- epilogue: O^T / l -> AO[q][d], b64 stores, all per-lane
#pragma unroll
    for (int tq = 0; tq < 2; ++tq) {
      float inv = 1.0f / lrow[tq];
      int q = qwave + tq * 16 + l15;
#pragma unroll
      for (int td = 0; td < 4; ++td) {
        bf16x4 ok = { (bf16)(o[tq][td][0] * inv), (bf16)(o[tq][td][1] * inv),
                      (bf16)(o[tq][td][2] * inv), (bf16)(o[tq][td][3] * inv) };
        *(bf16x4*)(AO + base + (size_t)q * C + td * 16 + l4 * 4) = ok;
      }
    }
  }
}

// ---------------- launch ----------------
extern "C" void kernel_launch(void* const* d_in, const int* in_sizes, int n_in,
                              void* d_out, int out_size, void* d_ws, size_t ws_size,
                              hipStream_t stream) {
  const float* x  = (const float*)d_in[0];
  const float* Wq = (const float*)d_in[1];
  const float* bq = (const float*)d_in[2];
  const float* Wk = (const float*)d_in[3];
  const float* bk = (const float*)d_in[4];
  const float* Wv = (const float*)d_in[5];
  const float* bv = (const float*)d_in[6];
  const float* Wo = (const float*)d_in[7];
  const float* bo = (const float*)d_in[8];

  bf16* ws = (bf16*)d_ws;
  const size_t M1 = (size_t)1 << 20;
  bf16* xb  = ws;            // 4M
  bf16* wqb = ws + 4 * M1;   // wq|wk|wv (1M each)
  bf16* wob = ws + 7 * M1;   // 1M
  bf16* Qp  = ws + 8 * M1;   // Q (4M) | K (4M)
  bf16* Vtp = ws + 16 * M1;  // Vt (4M), written by QKV gemm epilogue
  bf16* AOp = ws + 20 * M1;  // 4M

  // 1) cast inputs to bf16
  cast_all<<<8192, 256, 0, stream>>>(x, Wq, Wk, Wv, Wo, ws);
  // 2) fused QKV projection (Q pre-scaled; V written transposed to Vtp)
  gemm_bt<false, true, 128><<<dim3(24, 32), 256, 0, stream>>>(
      xb, wqb, bq, bk, bv, (void*)Qp, Vtp, 4096, 1024, 1024, 0.125f * LOG2E);
  // 3) causal flash attention (128q blocks, paired q-tiles, S^T+O^T layout)
  attn_kernel<<<512, 256, 0, stream>>>(Qp, Qp + 4 * M1, Vtp, AOp);
  // 4) output projection (fp32 out + bias)
  gemm_bt<true, false, 64><<<dim3(16, 32), 256, 0, stream>>>(
      AOp, wob, bo, nullptr, nullptr, d_out, nullptr, 4096, 1024, 1024, 1.0f);
}

// Round 8
// 191.785 us; speedup vs baseline: 1.0294x; 1.0294x over previous
//
#include <hip/hip_runtime.h>
#include <hip/hip_bf16.h>

// MHA: B=2, T=2048, C=1024, H=16, Dh=64. fp32 in/out, bf16 MFMA internally.
// ws layout (bf16 elems): [0,4M): xb. [4M,7M): wq|wk|wv. [7M,8M): wo.
// [8M,12M): Q. [12M,16M): K. [16M,20M): Vt (written by QKV gemm epilogue).
// [20M,24M): AO.  Total 48 MB.

typedef __bf16 bf16;
typedef __attribute__((ext_vector_type(8))) __bf16 bf16x8;
typedef __attribute__((ext_vector_type(4))) __bf16 bf16x4;
typedef __attribute__((ext_vector_type(4))) float floatx4;

#define LOG2E 1.44269504088896340736f

__device__ __forceinline__ void gl2lds16(const void* g, void* l) {
  __builtin_amdgcn_global_load_lds((const __attribute__((address_space(1))) void*)g,
                                   (__attribute__((address_space(3))) void*)l, 16, 0, 0);
}

// ---------------- cast fp32 -> bf16 (x | wq | wk | wv | wo) ----------------
__global__ __launch_bounds__(256) void cast_all(
    const float* __restrict__ x, const float* __restrict__ wq,
    const float* __restrict__ wk, const float* __restrict__ wv,
    const float* __restrict__ wo, bf16* __restrict__ dst)
{
  const size_t M1 = (size_t)1 << 20;
  size_t i4 = ((size_t)blockIdx.x * 256 + threadIdx.x) * 4;
  const float* src = x;
  size_t off = i4;
  if (i4 >= 4 * M1) {
    size_t r = i4 - 4 * M1;
    int seg = (int)(r >> 20);
    off = r & (M1 - 1);
    src = (seg == 0) ? wq : (seg == 1) ? wk : (seg == 2) ? wv : wo;
  }
  float4 f = *(const float4*)(src + off);
  bf16x4 o = { (bf16)f.x, (bf16)f.y, (bf16)f.z, (bf16)f.w };
  *(bf16x4*)(dst + i4) = o;
}

// ---------------- GEMM: out[m][n] = sum_k A[m][k]*W[n][k] + bias[n] ----------------
// BK=64, xor-swizzled 16B LDS groups (conflict-minimal reads), 32 MFMA/barrier.
// QKV: mat0 -> Q (bf16, pre-scaled), mat1 -> K, mat2 -> Vt[bh][d][t].
template<bool F32OUT, bool QKV, int BN>
__global__ __launch_bounds__(256, 3) void gemm_bt(
    const bf16* __restrict__ A, const bf16* __restrict__ Wb,
    const float* __restrict__ bq, const float* __restrict__ bk,
    const float* __restrict__ bv, void* __restrict__ outb,
    bf16* __restrict__ vt, int M, int N, int K, float qscale)
{
  __shared__ bf16 As[128 * 64];
  __shared__ bf16 Bs[BN * 64];
  const int tid = threadIdx.x;
  const int lane = tid & 63;
  const int wid = tid >> 6;
  const int l15 = lane & 15, l4 = lane >> 4;
  constexpr int I = (BN == 128) ? 4 : 2;
  const int wr = (BN == 128) ? (wid >> 1) : wid;
  const int wc = (BN == 128) ? (wid & 1) : 0;

  const bf16* W;
  const float* bias;
  float osc = 1.0f;
  int n0, mat = 0;
  bf16* outh;
  float* outf;
  if (QKV) {
    mat = blockIdx.x >> 3;
    n0 = (blockIdx.x & 7) << 7;
    W = Wb + ((size_t)mat << 20);
    bias = (mat == 0) ? bq : (mat == 1 ? bk : bv);
    if (mat == 0) osc = qscale;
    outh = (bf16*)outb + ((size_t)mat << 22);
    outf = nullptr;
  } else {
    n0 = blockIdx.x * BN;
    W = Wb;
    bias = bq;
    outf = (float*)outb;
    outh = nullptr;
  }
  const int m0 = blockIdx.y << 7;

  floatx4 acc[I][4] = {};

  for (int k0 = 0; k0 < K; k0 += 64) {
#pragma unroll
    for (int it = 0; it < 4; ++it) {
      int c = it * 256 + tid;
      int row = c >> 3, gs = ((c & 7) ^ (row & 7)) << 3;
      gl2lds16(A + (size_t)(m0 + row) * K + k0 + gs, As + c * 8);
    }
#pragma unroll
    for (int it = 0; it < BN / 32; ++it) {
      int c = it * 256 + tid;
      int row = c >> 3, gs = ((c & 7) ^ (row & 7)) << 3;
      gl2lds16(W + (size_t)(n0 + row) * K + k0 + gs, Bs + c * 8);
    }
    __syncthreads();
#pragma unroll
    for (int kk = 0; kk < 2; ++kk) {
      bf16x8 af[I], bfr[4];
#pragma unroll
      for (int i = 0; i < I; ++i) {
        int r = wr * (I * 16) + i * 16 + l15;
        int g = (kk * 4 + l4) ^ (r & 7);
        af[i] = *(const bf16x8*)(As + r * 64 + g * 8);
      }
#pragma unroll
      for (int j = 0; j < 4; ++j) {
        int r = wc * 64 + j * 16 + l15;
        int g = (kk * 4 + l4) ^ (r & 7);
        bfr[j] = *(const bf16x8*)(Bs + r * 64 + g * 8);
      }
#pragma unroll
      for (int i = 0; i < I; ++i)
#pragma unroll
        for (int j = 0; j < 4; ++j)
          acc[i][j] = __builtin_amdgcn_mfma_f32_16x16x32_bf16(af[i], bfr[j], acc[i][j], 0, 0, 0);
    }
    __syncthreads();
  }

  if (QKV && mat == 2) {
    // write Vt[bh][d][t]: lane's 4 rg rows are contiguous t -> b64 stores
#pragma unroll
    for (int j = 0; j < 4; ++j) {
      int col = n0 + wc * 64 + j * 16 + l15;
      float bv_ = bias[col];
      int h = col >> 6, d = col & 63;
#pragma unroll
      for (int i = 0; i < I; ++i) {
        int row = m0 + wr * (I * 16) + i * 16 + l4 * 4;
        int bb = row >> 11, t = row & 2047;
        bf16x4 pk;
#pragma unroll
        for (int rg = 0; rg < 4; ++rg) pk[rg] = (bf16)(acc[i][j][rg] + bv_);
        *(bf16x4*)(vt + (((size_t)(bb * 16 + h)) << 17) + ((size_t)d << 11) + t) = pk;
      }
    }
    return;
  }

#pragma unroll
  for (int j = 0; j < 4; ++j) {
    int col = n0 + wc * 64 + j * 16 + l15;
    float bv_ = bias[col];
#pragma unroll
    for (int i = 0; i < I; ++i) {
#pragma unroll
      for (int rg = 0; rg < 4; ++rg) {
        int row = m0 + wr * (I * 16) + i * 16 + l4 * 4 + rg;
        float v = (acc[i][j][rg] + bv_) * osc;
        if (F32OUT) outf[(size_t)row * N + col] = v;
        else        outh[(size_t)row * N + col] = (bf16)v;
      }
    }
  }
}

// ---------------- fused causal flash attention ----------------
// grid 256 1-D: bh = u&31 (fastest -> head-local L2/XCD), p = u>>5 (0..7),
// q-tile PAIR (15-p, p) of 128-row tiles -> all 16 tiles covered exactly
// once, uniform 36 K-tiles/block. 128 q-rows per seg, 32/wave (Q register
// B-frags reused across the K fragment reads). S and O both computed
// TRANSPOSED so softmax stats, alpha and 1/l are per-lane. K-tile 64,
// double-buffered gl2lds staging across the pair, ONE barrier per tile.
// Ps stride 68 (bank-minimal, 0 conflicts measured). Q pre-scaled by
// 1/sqrt(Dh)*log2e.
__global__ __launch_bounds__(256, 2) void attn_kernel(
    const bf16* __restrict__ Q, const bf16* __restrict__ Kg,
    const bf16* __restrict__ Vt, bf16* __restrict__ AO)
{
  constexpr int T = 2048, C = 1024;
  __shared__ bf16 Ks[2][64 * 64];   // [j][d], xor-swizzled 16B groups
  __shared__ bf16 Vts[2][64 * 64];  // [d][j], xor-swizzled 16B groups
  __shared__ bf16 Ps[4][32 * 68];   // per-wave P^T [q_local][j_local]

  const int tid = threadIdx.x;
  const int lane = tid & 63;
  const int w = tid >> 6;
  const int l15 = lane & 15, l4 = lane >> 4;

  const int u = blockIdx.x;
  const int bh = u & 31;
  const int p = u >> 5;                 // 0..7
  const size_t base = ((size_t)(bh >> 4) * T) * C + (bh & 15) * 64;
  const bf16* vtb = Vt + ((size_t)bh << 17);

  auto stageK = [&](int j0, int bufi) {
#pragma unroll
    for (int it = 0; it < 2; ++it) {
      int c = it * 256 + tid;
      int row = c >> 3, s = (c & 7) ^ (row & 7);
      gl2lds16(Kg + base + (size_t)(j0 + row) * C + s * 8, &Ks[bufi][c * 8]);
    }
  };
  auto stageV = [&](int j0, int bufi) {
#pragma unroll
    for (int it = 0; it < 2; ++it) {
      int c = it * 256 + tid;
      int row = c >> 3, s = (c & 7) ^ (row & 7);
      gl2lds16(vtb + ((size_t)row << 11) + j0 + s * 8, &Vts[bufi][c * 8]);
    }
  };

  const int qts[2] = { 15 - p, p };     // 128-row q-tiles, each exactly once
  int g = 0;  // global tile counter -> LDS buffer alternation
  stageK(0, 0);
  stageV(0, 0);

  for (int seg = 0; seg < 2; ++seg) {
    const int qt = qts[seg];
    const int q0 = qt << 7;
    const int nkt = 2 * qt + 2;
    const int qwave = q0 + w * 32;

    // Q B-frags in registers: wave w owns rows qwave + tq*16 + l15
    bf16x8 qf[2][2];
#pragma unroll
    for (int tq = 0; tq < 2; ++tq) {
      const bf16* qp = Q + base + (size_t)(qwave + tq * 16 + l15) * C + l4 * 8;
      qf[tq][0] = *(const bf16x8*)(qp);
      qf[tq][1] = *(const bf16x8*)(qp + 32);
    }
    floatx4 o[2][4] = {};      // O^T: rows d, col q
    float mrow[2] = {-1e38f, -1e38f};
    float lrow[2] = {0.f, 0.f};

    for (int jt = 0; jt < nkt; ++jt, ++g) {
      __syncthreads();  // staging of tile g visible; buf g^1 reads done
      const int cur = g & 1;
      if (jt + 1 < nkt) {
        stageK((jt + 1) << 6, cur ^ 1);
        stageV((jt + 1) << 6, cur ^ 1);
      } else if (seg == 0) {
        stageK(0, cur ^ 1);  // first tile of segment B
        stageV(0, cur ^ 1);
      }
      const int j0 = jt << 6;
      if (j0 > qwave + 31) continue;  // wave-uniform: fully masked tile

      // ---- S^T = K Q^T : s4[tj][tq], row j = tj*16+l4*4+rg, col q
      floatx4 s4[4][2] = {};
#pragma unroll
      for (int kk = 0; kk < 2; ++kk) {
        bf16x8 kf[4];
#pragma unroll
        for (int tj = 0; tj < 4; ++tj) {
          int r = tj * 16 + l15;
          int sl = (kk * 4 + l4) ^ (r & 7);
          kf[tj] = *(const bf16x8*)(&Ks[cur][r * 64 + sl * 8]);
        }
#pragma unroll
        for (int tj = 0; tj < 4; ++tj)
#pragma unroll
          for (int tq = 0; tq < 2; ++tq)
            s4[tj][tq] = __builtin_amdgcn_mfma_f32_16x16x32_bf16(kf[tj], qf[tq][kk], s4[tj][tq], 0, 0, 0);
      }

      // ---- causal mask (j > q): only near-diagonal tiles
      if (j0 + 63 > qwave) {
#pragma unroll
        for (int tj = 0; tj < 4; ++tj) {
          int j = j0 + tj * 16 + l4 * 4;
#pragma unroll
          for (int tq = 0; tq < 2; ++tq) {
            int q = qwave + tq * 16 + l15;
#pragma unroll
            for (int rg = 0; rg < 4; ++rg)
              if (j + rg > q) s4[tj][tq][rg] = -3e38f;
          }
        }
      }

      // ---- online softmax: lane owns row q, stats in-register + 2 shuffles
      float al[2];
#pragma unroll
      for (int tq = 0; tq < 2; ++tq) {
        float mx = -3e38f;
#pragma unroll
        for (int tj = 0; tj < 4; ++tj)
#pragma unroll
          for (int rg = 0; rg < 4; ++rg)
            mx = fmaxf(mx, s4[tj][tq][rg]);
        mx = fmaxf(mx, __shfl_xor(mx, 16, 64));
        mx = fmaxf(mx, __shfl_xor(mx, 32, 64));
        float mnew = fmaxf(mrow[tq], mx);
        al[tq] = __builtin_amdgcn_exp2f(mrow[tq] - mnew);
        mrow[tq] = mnew;
        float psum = 0.f;
#pragma unroll
        for (int tj = 0; tj < 4; ++tj)
#pragma unroll
          for (int rg = 0; rg < 4; ++rg) {
            float e = __builtin_amdgcn_exp2f(s4[tj][tq][rg] - mnew);
            s4[tj][tq][rg] = e;
            psum += e;
          }
        psum += __shfl_xor(psum, 16, 64);
        psum += __shfl_xor(psum, 32, 64);
        lrow[tq] = lrow[tq] * al[tq] + psum;
      }

      // ---- P -> LDS, packed b64 (rg contiguous): Ps[q_local][j_local]
#pragma unroll
      for (int tq = 0; tq < 2; ++tq)
#pragma unroll
        for (int tj = 0; tj < 4; ++tj) {
          bf16x4 pk = { (bf16)s4[tj][tq][0], (bf16)s4[tj][tq][1],
                        (bf16)s4[tj][tq][2], (bf16)s4[tj][tq][3] };
          *(bf16x4*)(&Ps[w][(tq * 16 + l15) * 68 + tj * 16 + l4 * 4]) = pk;
        }

      // ---- rescale O^T by alpha (per-lane, no shuffles)
#pragma unroll
      for (int tq = 0; tq < 2; ++tq)
#pragma unroll
        for (int td = 0; td < 4; ++td)
#pragma unroll
          for (int rg = 0; rg < 4; ++rg)
            o[tq][td][rg] *= al[tq];

      // ---- O^T += Vt P^T  (A = Vt frag shared across tq, B = P^T frag)
#pragma unroll
      for (int tk = 0; tk < 2; ++tk) {
        bf16x8 pf[2];
#pragma unroll
        for (int tq = 0; tq < 2; ++tq)
          pf[tq] = *(const bf16x8*)(&Ps[w][(tq * 16 + l15) * 68 + tk * 32 + l4 * 8]);
#pragma unroll
        for (int td = 0; td < 4; ++td) {
          int r = td * 16 + l15;
          int sl = (tk * 4 + l4) ^ (r & 7);
          bf16x8 vf = *(const bf16x8*)(&Vts[cur][r * 64 + sl * 8]);
#pragma unroll
          for (int tq = 0; tq < 2; ++tq)
            o[tq][td] = __builtin_amdgcn_mfma_f32_16x16x32_bf16(vf, pf[tq], o[tq][td], 0, 0, 0);
        }
      }
    }

    // ---- epilogue: O^T / l -> AO[q][d], b64 stores, all per-lane
#pragma unroll
    for (int tq = 0; tq < 2; ++tq) {
      float inv = 1.0f / lrow[tq];
      int q = qwave + tq * 16 + l15;
#pragma unroll
      for (int td = 0; td < 4; ++td) {
        bf16x4 ok = { (bf16)(o[tq][td][0] * inv), (bf16)(o[tq][td][1] * inv),
                      (bf16)(o[tq][td][2] * inv), (bf16)(o[tq][td][3] * inv) };
        *(bf16x4*)(AO + base + (size_t)q * C + td * 16 + l4 * 4) = ok;
      }
    }
  }
}

// ---------------- launch ----------------
extern "C" void kernel_launch(void* const* d_in, const int* in_sizes, int n_in,
                              void* d_out, int out_size, void* d_ws, size_t ws_size,
                              hipStream_t stream) {
  const float* x  = (const float*)d_in[0];
  const float* Wq = (const float*)d_in[1];
  const float* bq = (const float*)d_in[2];
  const float* Wk = (const float*)d_in[3];
  const float* bk = (const float*)d_in[4];
  const float* Wv = (const float*)d_in[5];
  const float* bv = (const float*)d_in[6];
  const float* Wo = (const float*)d_in[7];
  const float* bo = (const float*)d_in[8];

  bf16* ws = (bf16*)d_ws;
  const size_t M1 = (size_t)1 << 20;
  bf16* xb  = ws;            // 4M
  bf16* wqb = ws + 4 * M1;   // wq|wk|wv (1M each)
  bf16* wob = ws + 7 * M1;   // 1M
  bf16* Qp  = ws + 8 * M1;   // Q (4M) | K (4M)
  bf16* Vtp = ws + 16 * M1;  // Vt (4M), written by QKV gemm epilogue
  bf16* AOp = ws + 20 * M1;  // 4M

  // 1) cast inputs to bf16
  cast_all<<<8192, 256, 0, stream>>>(x, Wq, Wk, Wv, Wo, ws);
  // 2) fused QKV projection (Q pre-scaled; V written transposed to Vtp)
  gemm_bt<false, true, 128><<<dim3(24, 32), 256, 0, stream>>>(
      xb, wqb, bq, bk, bv, (void*)Qp, Vtp, 4096, 1024, 1024, 0.125f * LOG2E);
  // 3) causal flash attention (128q paired tiles x16, each ONCE; grid 256)
  attn_kernel<<<256, 256, 0, stream>>>(Qp, Qp + 4 * M1, Vtp, AOp);
  // 4) output projection (fp32 out + bias)
  gemm_bt<true, false, 64><<<dim3(16, 32), 256, 0, stream>>>(
      AOp, wob, bo, nullptr, nullptr, d_out, nullptr, 4096, 1024, 1024, 1.0f);
}

// Round 9
// 187.667 us; speedup vs baseline: 1.0520x; 1.0219x over previous
//
#include <hip/hip_runtime.h>
#include <hip/hip_bf16.h>

// MHA: B=2, T=2048, C=1024, H=16, Dh=64. fp32 in/out, bf16 MFMA internally.
// ws layout (bf16 elems): [0,4M): xb. [4M,7M): wq|wk|wv. [7M,8M): wo.
// [8M,12M): Q. [12M,16M): K. [16M,20M): Vt (written by QKV gemm epilogue).
// [20M,24M): AO.  Total 48 MB.

typedef __bf16 bf16;
typedef __attribute__((ext_vector_type(8))) __bf16 bf16x8;
typedef __attribute__((ext_vector_type(4))) __bf16 bf16x4;
typedef __attribute__((ext_vector_type(4))) float floatx4;

#define LOG2E 1.44269504088896340736f

__device__ __forceinline__ void gl2lds16(const void* g, void* l) {
  __builtin_amdgcn_global_load_lds((const __attribute__((address_space(1))) void*)g,
                                   (__attribute__((address_space(3))) void*)l, 16, 0, 0);
}

// ---------------- cast fp32 -> bf16 (x | wq | wk | wv | wo) ----------------
__global__ __launch_bounds__(256) void cast_all(
    const float* __restrict__ x, const float* __restrict__ wq,
    const float* __restrict__ wk, const float* __restrict__ wv,
    const float* __restrict__ wo, bf16* __restrict__ dst)
{
  const size_t M1 = (size_t)1 << 20;
  size_t i4 = ((size_t)blockIdx.x * 256 + threadIdx.x) * 4;
  const float* src = x;
  size_t off = i4;
  if (i4 >= 4 * M1) {
    size_t r = i4 - 4 * M1;
    int seg = (int)(r >> 20);
    off = r & (M1 - 1);
    src = (seg == 0) ? wq : (seg == 1) ? wk : (seg == 2) ? wv : wo;
  }
  float4 f = *(const float4*)(src + off);
  bf16x4 o = { (bf16)f.x, (bf16)f.y, (bf16)f.z, (bf16)f.w };
  *(bf16x4*)(dst + i4) = o;
}

// ---------------- GEMM: out[m][n] = sum_k A[m][k]*W[n][k] + bias[n] ----------------
// BK=64, xor-swizzled 16B LDS groups (conflict-minimal reads), 32 MFMA/barrier.
// QKV: mat0 -> Q (bf16, pre-scaled), mat1 -> K, mat2 -> Vt[bh][d][t].
template<bool F32OUT, bool QKV, int BN>
__global__ __launch_bounds__(256, 3) void gemm_bt(
    const bf16* __restrict__ A, const bf16* __restrict__ Wb,
    const float* __restrict__ bq, const float* __restrict__ bk,
    const float* __restrict__ bv, void* __restrict__ outb,
    bf16* __restrict__ vt, int M, int N, int K, float qscale)
{
  __shared__ bf16 As[128 * 64];
  __shared__ bf16 Bs[BN * 64];
  const int tid = threadIdx.x;
  const int lane = tid & 63;
  const int wid = tid >> 6;
  const int l15 = lane & 15, l4 = lane >> 4;
  constexpr int I = (BN == 128) ? 4 : 2;
  const int wr = (BN == 128) ? (wid >> 1) : wid;
  const int wc = (BN == 128) ? (wid & 1) : 0;

  const bf16* W;
  const float* bias;
  float osc = 1.0f;
  int n0, mat = 0;
  bf16* outh;
  float* outf;
  if (QKV) {
    mat = blockIdx.x >> 3;
    n0 = (blockIdx.x & 7) << 7;
    W = Wb + ((size_t)mat << 20);
    bias = (mat == 0) ? bq : (mat == 1 ? bk : bv);
    if (mat == 0) osc = qscale;
    outh = (bf16*)outb + ((size_t)mat << 22);
    outf = nullptr;
  } else {
    n0 = blockIdx.x * BN;
    W = Wb;
    bias = bq;
    outf = (float*)outb;
    outh = nullptr;
  }
  const int m0 = blockIdx.y << 7;

  floatx4 acc[I][4] = {};

  for (int k0 = 0; k0 < K; k0 += 64) {
#pragma unroll
    for (int it = 0; it < 4; ++it) {
      int c = it * 256 + tid;
      int row = c >> 3, gs = ((c & 7) ^ (row & 7)) << 3;
      gl2lds16(A + (size_t)(m0 + row) * K + k0 + gs, As + c * 8);
    }
#pragma unroll
    for (int it = 0; it < BN / 32; ++it) {
      int c = it * 256 + tid;
      int row = c >> 3, gs = ((c & 7) ^ (row & 7)) << 3;
      gl2lds16(W + (size_t)(n0 + row) * K + k0 + gs, Bs + c * 8);
    }
    __syncthreads();
#pragma unroll
    for (int kk = 0; kk < 2; ++kk) {
      bf16x8 af[I], bfr[4];
#pragma unroll
      for (int i = 0; i < I; ++i) {
        int r = wr * (I * 16) + i * 16 + l15;
        int g = (kk * 4 + l4) ^ (r & 7);
        af[i] = *(const bf16x8*)(As + r * 64 + g * 8);
      }
#pragma unroll
      for (int j = 0; j < 4; ++j) {
        int r = wc * 64 + j * 16 + l15;
        int g = (kk * 4 + l4) ^ (r & 7);
        bfr[j] = *(const bf16x8*)(Bs + r * 64 + g * 8);
      }
#pragma unroll
      for (int i = 0; i < I; ++i)
#pragma unroll
        for (int j = 0; j < 4; ++j)
          acc[i][j] = __builtin_amdgcn_mfma_f32_16x16x32_bf16(af[i], bfr[j], acc[i][j], 0, 0, 0);
    }
    __syncthreads();
  }

  if (QKV && mat == 2) {
    // write Vt[bh][d][t]: lane's 4 rg rows are contiguous t -> b64 stores
#pragma unroll
    for (int j = 0; j < 4; ++j) {
      int col = n0 + wc * 64 + j * 16 + l15;
      float bv_ = bias[col];
      int h = col >> 6, d = col & 63;
#pragma unroll
      for (int i = 0; i < I; ++i) {
        int row = m0 + wr * (I * 16) + i * 16 + l4 * 4;
        int bb = row >> 11, t = row & 2047;
        bf16x4 pk;
#pragma unroll
        for (int rg = 0; rg < 4; ++rg) pk[rg] = (bf16)(acc[i][j][rg] + bv_);
        *(bf16x4*)(vt + (((size_t)(bb * 16 + h)) << 17) + ((size_t)d << 11) + t) = pk;
      }
    }
    return;
  }

#pragma unroll
  for (int j = 0; j < 4; ++j) {
    int col = n0 + wc * 64 + j * 16 + l15;
    float bv_ = bias[col];
#pragma unroll
    for (int i = 0; i < I; ++i) {
#pragma unroll
      for (int rg = 0; rg < 4; ++rg) {
        int row = m0 + wr * (I * 16) + i * 16 + l4 * 4 + rg;
        float v = (acc[i][j][rg] + bv_) * osc;
        if (F32OUT) outf[(size_t)row * N + col] = v;
        else        outh[(size_t)row * N + col] = (bf16)v;
      }
    }
  }
}

// ---------------- fused causal flash attention ----------------
// grid 512 1-D: bh = u&31 (fastest -> head-local L2/XCD), p = u>>5 (0..15),
// qt = (p<8) ? 15-p : p-8  => round-robin dispatch co-locates qt-pairs
// (15-k, k) on one CU: uniform ~34 tiles/CU, 2 blocks/CU resident
// (independent barrier domains -> cross-block MFMA/VALU overlap).
// ONE 128-row q-tile per block, 32 q/wave (Q register B-frags amortize the
// K/V fragment reads over 2 MFMA columns). S and O both computed TRANSPOSED
// so softmax stats, alpha and 1/l are per-lane. K-tile 64, double-buffered
// gl2lds staging, ONE barrier per tile. Ps stride 68 (0 conflicts measured).
// Q pre-scaled by 1/sqrt(Dh)*log2e.
__global__ __launch_bounds__(256, 2) void attn_kernel(
    const bf16* __restrict__ Q, const bf16* __restrict__ Kg,
    const bf16* __restrict__ Vt, bf16* __restrict__ AO)
{
  constexpr int T = 2048, C = 1024;
  __shared__ bf16 Ks[2][64 * 64];   // [j][d], xor-swizzled 16B groups
  __shared__ bf16 Vts[2][64 * 64];  // [d][j], xor-swizzled 16B groups
  __shared__ bf16 Ps[4][32 * 68];   // per-wave P^T [q_local][j_local]

  const int tid = threadIdx.x;
  const int lane = tid & 63;
  const int w = tid >> 6;
  const int l15 = lane & 15, l4 = lane >> 4;

  const int u = blockIdx.x;
  const int bh = u & 31;
  const int p = u >> 5;                     // 0..15
  const int qt = (p < 8) ? (15 - p) : (p - 8);
  const int q0 = qt << 7;
  const int nkt = 2 * qt + 2;
  const size_t base = ((size_t)(bh >> 4) * T) * C + (bh & 15) * 64;
  const bf16* vtb = Vt + ((size_t)bh << 17);

  auto stageK = [&](int j0, int bufi) {
#pragma unroll
    for (int it = 0; it < 2; ++it) {
      int c = it * 256 + tid;
      int row = c >> 3, s = (c & 7) ^ (row & 7);
      gl2lds16(Kg + base + (size_t)(j0 + row) * C + s * 8, &Ks[bufi][c * 8]);
    }
  };
  auto stageV = [&](int j0, int bufi) {
#pragma unroll
    for (int it = 0; it < 2; ++it) {
      int c = it * 256 + tid;
      int row = c >> 3, s = (c & 7) ^ (row & 7);
      gl2lds16(vtb + ((size_t)row << 11) + j0 + s * 8, &Vts[bufi][c * 8]);
    }
  };

  const int qwave = q0 + w * 32;

  // Q B-frags in registers: wave w owns rows qwave + tq*16 + l15
  bf16x8 qf[2][2];
#pragma unroll
  for (int tq = 0; tq < 2; ++tq) {
    const bf16* qp = Q + base + (size_t)(qwave + tq * 16 + l15) * C + l4 * 8;
    qf[tq][0] = *(const bf16x8*)(qp);
    qf[tq][1] = *(const bf16x8*)(qp + 32);
  }
  floatx4 o[2][4] = {};      // O^T: rows d, col q
  float mrow[2] = {-1e38f, -1e38f};
  float lrow[2] = {0.f, 0.f};

  stageK(0, 0);
  stageV(0, 0);

  for (int jt = 0; jt < nkt; ++jt) {
    __syncthreads();  // staging of tile jt visible; buf jt^1 reads done
    const int cur = jt & 1;
    if (jt + 1 < nkt) {
      stageK((jt + 1) << 6, cur ^ 1);
      stageV((jt + 1) << 6, cur ^ 1);
    }
    const int j0 = jt << 6;
    if (j0 > qwave + 31) continue;  // wave-uniform: fully masked tile

    // ---- S^T = K Q^T : s4[tj][tq], row j = tj*16+l4*4+rg, col q
    floatx4 s4[4][2] = {};
#pragma unroll
    for (int kk = 0; kk < 2; ++kk) {
      bf16x8 kf[4];
#pragma unroll
      for (int tj = 0; tj < 4; ++tj) {
        int r = tj * 16 + l15;
        int sl = (kk * 4 + l4) ^ (r & 7);
        kf[tj] = *(const bf16x8*)(&Ks[cur][r * 64 + sl * 8]);
      }
#pragma unroll
      for (int tj = 0; tj < 4; ++tj)
#pragma unroll
        for (int tq = 0; tq < 2; ++tq)
          s4[tj][tq] = __builtin_amdgcn_mfma_f32_16x16x32_bf16(kf[tj], qf[tq][kk], s4[tj][tq], 0, 0, 0);
    }

    // ---- causal mask (j > q): only near-diagonal tiles
    if (j0 + 63 > qwave) {
#pragma unroll
      for (int tj = 0; tj < 4; ++tj) {
        int j = j0 + tj * 16 + l4 * 4;
#pragma unroll
        for (int tq = 0; tq < 2; ++tq) {
          int q = qwave + tq * 16 + l15;
#pragma unroll
          for (int rg = 0; rg < 4; ++rg)
            if (j + rg > q) s4[tj][tq][rg] = -3e38f;
        }
      }
    }

    // ---- online softmax: lane owns row q, stats in-register + 2 shuffles
    float al[2];
#pragma unroll
    for (int tq = 0; tq < 2; ++tq) {
      float mx = -3e38f;
#pragma unroll
      for (int tj = 0; tj < 4; ++tj)
#pragma unroll
        for (int rg = 0; rg < 4; ++rg)
          mx = fmaxf(mx, s4[tj][tq][rg]);
      mx = fmaxf(mx, __shfl_xor(mx, 16, 64));
      mx = fmaxf(mx, __shfl_xor(mx, 32, 64));
      float mnew = fmaxf(mrow[tq], mx);
      al[tq] = __builtin_amdgcn_exp2f(mrow[tq] - mnew);
      mrow[tq] = mnew;
      float psum = 0.f;
#pragma unroll
      for (int tj = 0; tj < 4; ++tj)
#pragma unroll
        for (int rg = 0; rg < 4; ++rg) {
          float e = __builtin_amdgcn_exp2f(s4[tj][tq][rg] - mnew);
          s4[tj][tq][rg] = e;
          psum += e;
        }
      psum += __shfl_xor(psum, 16, 64);
      psum += __shfl_xor(psum, 32, 64);
      lrow[tq] = lrow[tq] * al[tq] + psum;
    }

    // ---- P -> LDS, packed b64 (rg contiguous): Ps[q_local][j_local]
#pragma unroll
    for (int tq = 0; tq < 2; ++tq)
#pragma unroll
      for (int tj = 0; tj < 4; ++tj) {
        bf16x4 pk = { (bf16)s4[tj][tq][0], (bf16)s4[tj][tq][1],
                      (bf16)s4[tj][tq][2], (bf16)s4[tj][tq][3] };
        *(bf16x4*)(&Ps[w][(tq * 16 + l15) * 68 + tj * 16 + l4 * 4]) = pk;
      }

    // ---- rescale O^T by alpha (per-lane, no shuffles)
#pragma unroll
    for (int tq = 0; tq < 2; ++tq)
#pragma unroll
      for (int td = 0; td < 4; ++td)
#pragma unroll
        for (int rg = 0; rg < 4; ++rg)
          o[tq][td][rg] *= al[tq];

    // ---- O^T += Vt P^T  (A = Vt frag shared across tq, B = P^T frag)
#pragma unroll
    for (int tk = 0; tk < 2; ++tk) {
      bf16x8 pf[2];
#pragma unroll
      for (int tq = 0; tq < 2; ++tq)
        pf[tq] = *(const bf16x8*)(&Ps[w][(tq * 16 + l15) * 68 + tk * 32 + l4 * 8]);
#pragma unroll
      for (int td = 0; td < 4; ++td) {
        int r = td * 16 + l15;
        int sl = (tk * 4 + l4) ^ (r & 7);
        bf16x8 vf = *(const bf16x8*)(&Vts[cur][r * 64 + sl * 8]);
#pragma unroll
        for (int tq = 0; tq < 2; ++tq)
          o[tq][td] = __builtin_amdgcn_mfma_f32_16x16x32_bf16(vf, pf[tq], o[tq][td], 0, 0, 0);
      }
    }
  }

  // ---- epilogue: O^T / l -> AO[q][d], b64 stores, all per-lane
#pragma unroll
  for (int tq = 0; tq < 2; ++tq) {
    float inv = 1.0f / lrow[tq];
    int q = qwave + tq * 16 + l15;
#pragma unroll
    for (int td = 0; td < 4; ++td) {
      bf16x4 ok = { (bf16)(o[tq][td][0] * inv), (bf16)(o[tq][td][1] * inv),
                    (bf16)(o[tq][td][2] * inv), (bf16)(o[tq][td][3] * inv) };
      *(bf16x4*)(AO + base + (size_t)q * C + td * 16 + l4 * 4) = ok;
    }
  }
}

// ---------------- launch ----------------
extern "C" void kernel_launch(void* const* d_in, const int* in_sizes, int n_in,
                              void* d_out, int out_size, void* d_ws, size_t ws_size,
                              hipStream_t stream) {
  const float* x  = (const float*)d_in[0];
  const float* Wq = (const float*)d_in[1];
  const float* bq = (const float*)d_in[2];
  const float* Wk = (const float*)d_in[3];
  const float* bk = (const float*)d_in[4];
  const float* Wv = (const float*)d_in[5];
  const float* bv = (const float*)d_in[6];
  const float* Wo = (const float*)d_in[7];
  const float* bo = (const float*)d_in[8];

  bf16* ws = (bf16*)d_ws;
  const size_t M1 = (size_t)1 << 20;
  bf16* xb  = ws;            // 4M
  bf16* wqb = ws + 4 * M1;   // wq|wk|wv (1M each)
  bf16* wob = ws + 7 * M1;   // 1M
  bf16* Qp  = ws + 8 * M1;   // Q (4M) | K (4M)
  bf16* Vtp = ws + 16 * M1;  // Vt (4M), written by QKV gemm epilogue
  bf16* AOp = ws + 20 * M1;  // 4M

  // 1) cast inputs to bf16
  cast_all<<<8192, 256, 0, stream>>>(x, Wq, Wk, Wv, Wo, ws);
  // 2) fused QKV projection (Q pre-scaled; V written transposed to Vtp)
  gemm_bt<false, true, 128><<<dim3(24, 32), 256, 0, stream>>>(
      xb, wqb, bq, bk, bv, (void*)Qp, Vtp, 4096, 1024, 1024, 0.125f * LOG2E);
  // 3) causal flash attention (one 128q tile/block, grid 512, 2 blocks/CU)
  attn_kernel<<<512, 256, 0, stream>>>(Qp, Qp + 4 * M1, Vtp, AOp);
  // 4) output projection (fp32 out + bias)
  gemm_bt<true, false, 64><<<dim3(16, 32), 256, 0, stream>>>(
      AOp, wob, bo, nullptr, nullptr, d_out, nullptr, 4096, 1024, 1024, 1.0f);
}